// Round 4
// baseline (2098.416 us; speedup 1.0000x reference)
//
#include <hip/hip_runtime.h>
#include <hip/hip_bf16.h>

typedef unsigned short u16;
typedef unsigned int   u32;

using bf16x8 = __attribute__((ext_vector_type(8))) short;  // 8 bf16 (4 VGPRs)
using f32x4  = __attribute__((ext_vector_type(4))) float;  // MFMA accum
using fvec4  = __attribute__((ext_vector_type(4))) float;
using u16x4  = __attribute__((ext_vector_type(4))) unsigned short;

#define BSZ   8192
#define DIN   2048
#define MMD   1600
#define NCH   20
#define CSZ   80
#define DOUT  3000

// ---------- bf16 helpers ----------
__device__ __forceinline__ float bf2f(u16 u) {
    u32 x = ((u32)u) << 16; float f; __builtin_memcpy(&f, &x, 4); return f;
}
__device__ __forceinline__ u16 f2bf(float f) {  // RNE
    u32 x; __builtin_memcpy(&x, &f, 4);
    u32 r = x + 0x7fffu + ((x >> 16) & 1u);
    return (u16)(r >> 16);
}

// ---------- async global->LDS, 16B/lane, wave-uniform LDS base ----------
__device__ __forceinline__ void gl2lds16(const void* g, const void* l) {
    __builtin_amdgcn_global_load_lds(
        (const __attribute__((address_space(1))) u32*)g,
        (__attribute__((address_space(3))) u32*)l, 16, 0, 0);
}

// ---------- converters ----------
__global__ void cast_bf16_k(const float* __restrict__ src, u16* __restrict__ dst, int n4) {
    int i = blockIdx.x * blockDim.x + threadIdx.x;
    if (i < n4) {
        fvec4 v = ((const fvec4*)src)[i];
        u16x4 o;
        o.x = f2bf(v.x); o.y = f2bf(v.y); o.z = f2bf(v.z); o.w = f2bf(v.w);
        ((u16x4*)dst)[i] = o;
    }
}

// src: [K][N] f32 -> dst: [Npad][K] bf16, zero rows for n>=N.
__global__ void transpose_cast_k(const float* __restrict__ src, u16* __restrict__ dst,
                                 int K, int N) {
    __shared__ float t[32][33];
    int k0 = blockIdx.x * 32, n0 = blockIdx.y * 32;
    int tx = threadIdx.x & 31, ty = threadIdx.x >> 5;
#pragma unroll
    for (int r = 0; r < 4; r++) {
        int n = n0 + tx;
        float v = (n < N) ? src[(size_t)(k0 + ty + 8 * r) * N + n] : 0.f;
        t[ty + 8 * r][tx] = v;
    }
    __syncthreads();
#pragma unroll
    for (int r = 0; r < 4; r++)
        dst[(size_t)(n0 + ty + 8 * r) * K + k0 + tx] = f2bf(t[tx][ty + 8 * r]);
}

// ---------- m97-style GEMM with XOR-swizzled LDS (unchanged) ----------
template<bool OUT_BF16>
__global__ __launch_bounds__(256, 2) void gemm_bt_k(
    const u16* __restrict__ A, const u16* __restrict__ BT,
    const float* __restrict__ bias, void* __restrict__ C, int K, int N) {
    __shared__ __align__(16) u16 As[128 * 64];
    __shared__ __align__(16) u16 Bs[128 * 64];
    const int tid = threadIdx.x, w = tid >> 6, lane = tid & 63;
    const int lr = lane & 15, lk = lane >> 4, s7 = lr & 7;
    const int m0 = blockIdx.x * 128, n0 = blockIdx.y * 128;
    const int mh = (w >> 1) * 64, nh = (w & 1) * 64;
    const int so = (lane & 7) ^ (lane >> 3);
    int arow[4], brow[4];
#pragma unroll
    for (int i = 0; i < 4; i++) { arow[i] = (mh + i * 16 + lr) * 64; brow[i] = (nh + i * 16 + lr) * 64; }
    f32x4 acc[4][4] = {};
    const u16* Ag = A + (size_t)m0 * K;
    const u16* Bg = BT + (size_t)n0 * K;
    const int nslab = K >> 6;
    for (int kt = 0; kt < nslab; ++kt) {
        const int k0 = kt * 64;
        __syncthreads();
#pragma unroll
        for (int q = 0; q < 4; q++) {
            int ch = w * 4 + q;
            int row = ch * 8 + (lane >> 3);
            gl2lds16(Ag + (size_t)row * K + k0 + so * 8, As + ch * 512);
            gl2lds16(Bg + (size_t)row * K + k0 + so * 8, Bs + ch * 512);
        }
        __syncthreads();
#pragma unroll
        for (int ks = 0; ks < 64; ks += 32) {
            const int px = (((ks >> 3) + lk) ^ s7) * 8;
            bf16x8 av[4], bv[4];
#pragma unroll
            for (int i = 0; i < 4; i++) av[i] = *(const bf16x8*)(As + arow[i] + px);
#pragma unroll
            for (int j = 0; j < 4; j++) bv[j] = *(const bf16x8*)(Bs + brow[j] + px);
#pragma unroll
            for (int i = 0; i < 4; i++)
#pragma unroll
                for (int j = 0; j < 4; j++)
                    acc[i][j] = __builtin_amdgcn_mfma_f32_16x16x32_bf16(av[i], bv[j], acc[i][j], 0, 0, 0);
        }
    }
#pragma unroll
    for (int j = 0; j < 4; j++) {
        int n = n0 + nh + j * 16 + lr;
        if (n < N) {
            float bv = bias[n];
#pragma unroll
            for (int i = 0; i < 4; i++) {
                int mb = m0 + mh + i * 16 + lk * 4;
#pragma unroll
                for (int r = 0; r < 4; r++) {
                    float v = acc[i][j][r] + bv;
                    if (OUT_BF16) ((u16*)C)[(size_t)(mb + r) * N + n] = f2bf(v);
                    else          ((float*)C)[(size_t)(mb + r) * N + n] = v;
                }
            }
        }
    }
}

// ---------- bilinear, v4: BM=256, 64 rows/wave, spill-proofed ----------
// z = sum_s h0[:,s] * (h1 @ Wb[c,:,s,:]^T).
// v4 vs v3 (which spilled: 128-arch split, 300MB scratch WRITE_SIZE):
//  * P[4][3] -> P[4]: j processed one 16-col tile at a time (-32 VGPR).
//  * h0 loaded as bf16 PAIRS (one u32 covers cols s,s+1): 8 loads/s and the
//    PA/PB double-buffer is 32 VGPRs total, rotated by name in an unroll-4
//    body (no copies -> no early waits).
//  * Ws row = 96 u16 = 12 octets exactly (no 13th pad octet): 960 positions,
//    4 descriptors/wave, EVERY wave issues exactly 4 gl2lds.
//  * boff -> 1 reg + compile-time j*1536 + st*32 immediates.
// Counted wait: per step in-flight = 4 stage + 16 h0 = vmcnt(20), retiring
// exactly the previous step's stage (+ the 2-step-old h0 pair on even steps).
// Est. ~225 live VGPRs < 256 @ (256,2).
__global__ __launch_bounds__(256, 2) void bilinear_k(
    const u16* __restrict__ h0g, const u16* __restrict__ h1g,
    const u16* __restrict__ Wbg, const float* __restrict__ bbg,
    u16* __restrict__ zg) {
    constexpr int WROW = 96;              // u16 per Ws row (12 octets)
    constexpr int WBUF = CSZ * WROW;      // 7680 u16 per buffer
    __shared__ __align__(16) u16 Ws[3 * WBUF];   // 46080 B
    const int tid = threadIdx.x, w = tid >> 6, lane = tid & 63;
    const int lr = lane & 15, lk = lane >> 4;
    const int m0 = blockIdx.x * 256, c = blockIdx.y;

    // zero pad octets (o = 10, 11) of every row, all 3 buffers (480 stores)
#pragma unroll
    for (int t = 0; t < 2; ++t) {
        int q = t * 256 + tid;
        if (q < 480) {
            int b = q / 160, r2 = q - b * 160;
            *(fvec4*)(Ws + b * WBUF + (r2 >> 1) * WROW + 80 + (r2 & 1) * 8) =
                (fvec4){0.f, 0.f, 0.f, 0.f};
        }
    }

    // Ws staging: 960 octet-positions (80 rows x 12), real o<10 (800).
    // it<3: p = it*256+tid. it==3: 192 tail octets, 48/wave (lanes 0..47).
    // Every wave has active lanes in all 4 its -> exactly 4 gl2lds/wave.
    const u16* WgBase = Wbg + (size_t)c * CSZ * 6400;
    const u16* wsrc[4];
    bool wok[4];
    int wdst[4];
#pragma unroll
    for (int it = 0; it < 4; ++it) {
        int p, dstoct;
        if (it < 3) { p = it * 256 + tid;                      dstoct = it * 256 + w * 64; }
        else        { p = 768 + w * 48 + (lane < 48 ? lane : 0); dstoct = 768 + w * 48; }
        int row = p / 12, o = p - row * 12;
        wok[it] = (o < 10) && (it < 3 || lane < 48);
        wsrc[it] = WgBase + (size_t)row * 6400 + o * 8;  // advance +80 per s
        wdst[it] = dstoct * 8;
    }

    // hoist A fragments (s-invariant) straight from global; zero the k>=80 pad
    bf16x8 av[4][3];
    const u16* h1base = h1g + (size_t)m0 * MMD + c * CSZ;
#pragma unroll
    for (int i = 0; i < 4; ++i) {
        const u16* rowp = h1base + (size_t)(w * 64 + i * 16 + lr) * MMD;
#pragma unroll
        for (int st = 0; st < 3; ++st) {
            if (st == 2 && lk >= 2) {
                av[i][st] = (bf16x8){0, 0, 0, 0, 0, 0, 0, 0};
            } else {
                av[i][st] = *(const bf16x8*)(rowp + st * 32 + lk * 8);
            }
        }
    }

    // h0 addressing: 16 uniform (SGPR) dword bases + ONE per-lane dword offset
    const u32* hb32[16];
#pragma unroll
    for (int i = 0; i < 4; ++i)
#pragma unroll
        for (int r = 0; r < 4; ++r)
            hb32[i * 4 + r] = (const u32*)(h0g + (size_t)(m0 + i * 16 + r) * MMD + c * CSZ);
    const int voff32 = (w * 64 + lk * 4) * (MMD / 2);

    // prologue: stage buf0 (s=0); h0 pair (cols 0,1) -> PA
#pragma unroll
    for (int it = 0; it < 4; ++it) {
        if (wok[it]) gl2lds16(wsrc[it], Ws + wdst[it]);
        wsrc[it] += CSZ;
    }
    u32 PA[16], PB[16];
#pragma unroll
    for (int kk = 0; kk < 16; ++kk) PA[kk] = hb32[kk][voff32];

    __syncthreads();   // full drain: pads + buf0 + av + PA all resolved

    const int boff0 = lr * WROW + lk * 8;
    f32x4 z[4][5] = {};
    const f32x4 zf = {0.f, 0.f, 0.f, 0.f};
    int bufR = 0;

#define STAGE_WS()                                                          \
    {                                                                       \
        u16* wW = Ws + ((bufR + 1 == 3) ? 0 : bufR + 1) * WBUF;             \
        _Pragma("unroll")                                                   \
        for (int it = 0; it < 4; ++it) {                                    \
            if (wok[it]) gl2lds16(wsrc[it], wW + wdst[it]);                 \
            wsrc[it] += CSZ;                                                \
        }                                                                   \
    }

#define COMPUTE(PU, ISHI)                                                   \
    {                                                                       \
        __builtin_amdgcn_s_barrier();                                       \
        asm volatile("" ::: "memory");                                      \
        const u16* Wr = Ws + bufR * WBUF;                                   \
        float h0f[16];                                                      \
        _Pragma("unroll")                                                   \
        for (int kk = 0; kk < 16; ++kk) {                                   \
            u32 bits = (ISHI) ? (PU[kk] & 0xffff0000u) : (PU[kk] << 16);    \
            __builtin_memcpy(&h0f[kk], &bits, 4);                           \
        }                                                                   \
        _Pragma("unroll")                                                   \
        for (int j = 0; j < 5; ++j) {                                       \
            bf16x8 bv0 = *(const bf16x8*)(Wr + boff0 + j * 1536);           \
            bf16x8 bv1 = *(const bf16x8*)(Wr + boff0 + j * 1536 + 32);      \
            bf16x8 bv2 = *(const bf16x8*)(Wr + boff0 + j * 1536 + 64);      \
            f32x4 P[4];                                                     \
            _Pragma("unroll")                                               \
            for (int i = 0; i < 4; ++i)                                     \
                P[i] = __builtin_amdgcn_mfma_f32_16x16x32_bf16(av[i][0], bv0, zf, 0, 0, 0); \
            _Pragma("unroll")                                               \
            for (int i = 0; i < 4; ++i)                                     \
                P[i] = __builtin_amdgcn_mfma_f32_16x16x32_bf16(av[i][1], bv1, P[i], 0, 0, 0); \
            _Pragma("unroll")                                               \
            for (int i = 0; i < 4; ++i)                                     \
                P[i] = __builtin_amdgcn_mfma_f32_16x16x32_bf16(av[i][2], bv2, P[i], 0, 0, 0); \
            _Pragma("unroll")                                               \
            for (int i = 0; i < 4; ++i)                                     \
                _Pragma("unroll")                                           \
                for (int r = 0; r < 4; ++r)                                 \
                    z[i][j][r] += h0f[i * 4 + r] * P[i][r];                 \
        }                                                                   \
        bufR = (bufR == 2) ? 0 : bufR + 1;                                  \
    }

// even step S (S in {4k,4k+2}, so S<=78): stage S+1, prefetch h0 pair -> PL
#define STEP_EVEN(S, PU, PL)                                                \
    {                                                                       \
        STAGE_WS();                                                         \
        const int ci = ((S) + 2 < 80) ? (((S) + 2) >> 1) : 0;               \
        _Pragma("unroll")                                                   \
        for (int kk = 0; kk < 16; ++kk) PL[kk] = hb32[kk][voff32 + ci];     \
        asm volatile("s_waitcnt vmcnt(20)" ::: "memory");                   \
        COMPUTE(PU, 0)                                                      \
    }

// odd step S: stage S+1 unless last (S==79)
#define STEP_ODD(S, PU, LASTQ)                                              \
    {                                                                       \
        if (!(LASTQ)) {                                                     \
            STAGE_WS();                                                     \
            asm volatile("s_waitcnt vmcnt(20)" ::: "memory");               \
        } else {                                                            \
            asm volatile("s_waitcnt vmcnt(0)" ::: "memory");                \
        }                                                                   \
        COMPUTE(PU, 1)                                                      \
    }

#pragma unroll 1
    for (int k4 = 0; k4 < 20; ++k4) {
        const int s0 = k4 * 4;
        STEP_EVEN(s0,     PA, PB)
        STEP_ODD (s0 + 1, PA, false)
        STEP_EVEN(s0 + 2, PB, PA)
        STEP_ODD (s0 + 3, PB, (k4 == 19))
    }
#undef STEP_ODD
#undef STEP_EVEN
#undef COMPUTE
#undef STAGE_WS

    // epilogue: +bb, signed sqrt, per-row L2 norm over the 80 chunk cols
    float bbv[5];
#pragma unroll
    for (int j = 0; j < 5; j++) bbv[j] = bbg[c * CSZ + j * 16 + lr];
    float sq[4][4] = {};
#pragma unroll
    for (int i = 0; i < 4; i++)
#pragma unroll
        for (int j = 0; j < 5; j++)
#pragma unroll
            for (int r = 0; r < 4; r++) {
                float v = z[i][j][r] + bbv[j];
                float a = sqrtf(fabsf(v));
                v = (v < 0.f) ? -a : a;
                z[i][j][r] = v;
                sq[i][r] += v * v;
            }
#pragma unroll
    for (int d = 1; d < 16; d <<= 1)
#pragma unroll
        for (int i = 0; i < 4; i++)
#pragma unroll
            for (int r = 0; r < 4; r++)
                sq[i][r] += __shfl_xor(sq[i][r], d, 64);
    float sc[4][4];
#pragma unroll
    for (int i = 0; i < 4; i++)
#pragma unroll
        for (int r = 0; r < 4; r++)
            sc[i][r] = 1.f / fmaxf(sqrtf(sq[i][r]), 1e-12f);
#pragma unroll
    for (int i = 0; i < 4; i++)
#pragma unroll
        for (int r = 0; r < 4; r++) {
            int row = m0 + w * 64 + i * 16 + lk * 4 + r;
#pragma unroll
            for (int j = 0; j < 5; j++) {
                int col = c * CSZ + j * 16 + lr;
                zg[(size_t)row * MMD + col] = f2bf(z[i][j][r] * sc[i][r]);
            }
        }
}

// ---------- launcher ----------
extern "C" void kernel_launch(void* const* d_in, const int* in_sizes, int n_in,
                              void* d_out, int out_size, void* d_ws, size_t ws_size,
                              hipStream_t stream) {
    (void)in_sizes; (void)n_in; (void)out_size; (void)ws_size;
    const float* x0 = (const float*)d_in[0];
    const float* x1 = (const float*)d_in[1];
    const float* W0 = (const float*)d_in[2];
    const float* b0 = (const float*)d_in[3];
    const float* W1 = (const float*)d_in[4];
    const float* b1 = (const float*)d_in[5];
    const float* Wb = (const float*)d_in[6];
    const float* bb = (const float*)d_in[7];
    const float* Wo = (const float*)d_in[8];
    const float* bo = (const float*)d_in[9];

    char* ws = (char*)d_ws;
    size_t off = 0;
    auto alloc = [&](size_t bytes) { void* p = ws + off; off += (bytes + 255) & ~(size_t)255; return p; };
    u16* x0b = (u16*)alloc((size_t)BSZ * DIN * 2);
    u16* x1b = (u16*)alloc((size_t)BSZ * DIN * 2);
    u16* W0T = (u16*)alloc((size_t)1664 * DIN * 2);
    u16* W1T = (u16*)alloc((size_t)1664 * DIN * 2);
    u16* WbB = (u16*)alloc((size_t)NCH * CSZ * 6400 * 2);
    u16* WoT = (u16*)alloc((size_t)3072 * MMD * 2);
    u16* h0  = (u16*)alloc((size_t)BSZ * MMD * 2);
    u16* h1  = (u16*)alloc((size_t)BSZ * MMD * 2);
    u16* z   = x0b;  // alias: x0b dead after first GEMM

    cast_bf16_k<<<dim3(16384), dim3(256), 0, stream>>>(x0, x0b, (BSZ * DIN) / 4);
    cast_bf16_k<<<dim3(16384), dim3(256), 0, stream>>>(x1, x1b, (BSZ * DIN) / 4);
    cast_bf16_k<<<dim3(10000), dim3(256), 0, stream>>>(Wb, WbB, (NCH * CSZ * 6400) / 4);
    transpose_cast_k<<<dim3(DIN / 32, 1664 / 32), dim3(256), 0, stream>>>(W0, W0T, DIN, MMD);
    transpose_cast_k<<<dim3(DIN / 32, 1664 / 32), dim3(256), 0, stream>>>(W1, W1T, DIN, MMD);
    transpose_cast_k<<<dim3(MMD / 32, 3072 / 32), dim3(256), 0, stream>>>(Wo, WoT, MMD, DOUT);
    gemm_bt_k<true><<<dim3(BSZ / 128, 13), dim3(256), 0, stream>>>(x0b, W0T, b0, h0, DIN, MMD);
    gemm_bt_k<true><<<dim3(BSZ / 128, 13), dim3(256), 0, stream>>>(x1b, W1T, b1, h1, DIN, MMD);
    bilinear_k<<<dim3(BSZ / 256, NCH), dim3(256), 0, stream>>>(h0, h1, WbB, bb, z);
    gemm_bt_k<false><<<dim3(BSZ / 128, 24), dim3(256), 0, stream>>>(z, WoT, bo, d_out, MMD, DOUT);
}

// Round 5
// 705.370 us; speedup vs baseline: 2.9749x; 2.9749x over previous
//
#include <hip/hip_runtime.h>
#include <hip/hip_bf16.h>

typedef unsigned short u16;
typedef unsigned int   u32;

using bf16x8 = __attribute__((ext_vector_type(8))) short;  // 8 bf16 (4 VGPRs)
using f32x4  = __attribute__((ext_vector_type(4))) float;  // MFMA accum
using fvec4  = __attribute__((ext_vector_type(4))) float;
using u16x4  = __attribute__((ext_vector_type(4))) unsigned short;

#define BSZ   8192
#define DIN   2048
#define MMD   1600
#define NCH   20
#define CSZ   80
#define DOUT  3000

// ---------- bf16 helpers ----------
__device__ __forceinline__ float bf2f(u16 u) {
    u32 x = ((u32)u) << 16; float f; __builtin_memcpy(&f, &x, 4); return f;
}
__device__ __forceinline__ u16 f2bf(float f) {  // RNE
    u32 x; __builtin_memcpy(&x, &f, 4);
    u32 r = x + 0x7fffu + ((x >> 16) & 1u);
    return (u16)(r >> 16);
}

// ---------- async global->LDS, 16B/lane, wave-uniform LDS base ----------
__device__ __forceinline__ void gl2lds16(const void* g, const void* l) {
    __builtin_amdgcn_global_load_lds(
        (const __attribute__((address_space(1))) u32*)g,
        (__attribute__((address_space(3))) u32*)l, 16, 0, 0);
}

// ---------- converters ----------
__global__ void cast_bf16_k(const float* __restrict__ src, u16* __restrict__ dst, int n4) {
    int i = blockIdx.x * blockDim.x + threadIdx.x;
    if (i < n4) {
        fvec4 v = ((const fvec4*)src)[i];
        u16x4 o;
        o.x = f2bf(v.x); o.y = f2bf(v.y); o.z = f2bf(v.z); o.w = f2bf(v.w);
        ((u16x4*)dst)[i] = o;
    }
}

// src: [K][N] f32 -> dst: [Npad][K] bf16, zero rows for n>=N.
__global__ void transpose_cast_k(const float* __restrict__ src, u16* __restrict__ dst,
                                 int K, int N) {
    __shared__ float t[32][33];
    int k0 = blockIdx.x * 32, n0 = blockIdx.y * 32;
    int tx = threadIdx.x & 31, ty = threadIdx.x >> 5;
#pragma unroll
    for (int r = 0; r < 4; r++) {
        int n = n0 + tx;
        float v = (n < N) ? src[(size_t)(k0 + ty + 8 * r) * N + n] : 0.f;
        t[ty + 8 * r][tx] = v;
    }
    __syncthreads();
#pragma unroll
    for (int r = 0; r < 4; r++)
        dst[(size_t)(n0 + ty + 8 * r) * K + k0 + tx] = f2bf(t[tx][ty + 8 * r]);
}

// ---------- m97-style GEMM with XOR-swizzled LDS ----------
// OUT_MODE: 0 = f32 [M][N], 1 = bf16 [M][N], 2 = bf16 TRANSPOSED [N][BSZ]
// (mode 2: one u16x4 store replaces 4 scattered 2B stores; used for h0T)
template<int OUT_MODE>
__global__ __launch_bounds__(256, 2) void gemm_bt_k(
    const u16* __restrict__ A, const u16* __restrict__ BT,
    const float* __restrict__ bias, void* __restrict__ C, int K, int N) {
    __shared__ __align__(16) u16 As[128 * 64];
    __shared__ __align__(16) u16 Bs[128 * 64];
    const int tid = threadIdx.x, w = tid >> 6, lane = tid & 63;
    const int lr = lane & 15, lk = lane >> 4, s7 = lr & 7;
    const int m0 = blockIdx.x * 128, n0 = blockIdx.y * 128;
    const int mh = (w >> 1) * 64, nh = (w & 1) * 64;
    const int so = (lane & 7) ^ (lane >> 3);
    int arow[4], brow[4];
#pragma unroll
    for (int i = 0; i < 4; i++) { arow[i] = (mh + i * 16 + lr) * 64; brow[i] = (nh + i * 16 + lr) * 64; }
    f32x4 acc[4][4] = {};
    const u16* Ag = A + (size_t)m0 * K;
    const u16* Bg = BT + (size_t)n0 * K;
    const int nslab = K >> 6;
    for (int kt = 0; kt < nslab; ++kt) {
        const int k0 = kt * 64;
        __syncthreads();
#pragma unroll
        for (int q = 0; q < 4; q++) {
            int ch = w * 4 + q;
            int row = ch * 8 + (lane >> 3);
            gl2lds16(Ag + (size_t)row * K + k0 + so * 8, As + ch * 512);
            gl2lds16(Bg + (size_t)row * K + k0 + so * 8, Bs + ch * 512);
        }
        __syncthreads();
#pragma unroll
        for (int ks = 0; ks < 64; ks += 32) {
            const int px = (((ks >> 3) + lk) ^ s7) * 8;
            bf16x8 av[4], bv[4];
#pragma unroll
            for (int i = 0; i < 4; i++) av[i] = *(const bf16x8*)(As + arow[i] + px);
#pragma unroll
            for (int j = 0; j < 4; j++) bv[j] = *(const bf16x8*)(Bs + brow[j] + px);
#pragma unroll
            for (int i = 0; i < 4; i++)
#pragma unroll
                for (int j = 0; j < 4; j++)
                    acc[i][j] = __builtin_amdgcn_mfma_f32_16x16x32_bf16(av[i], bv[j], acc[i][j], 0, 0, 0);
        }
    }
#pragma unroll
    for (int j = 0; j < 4; j++) {
        int n = n0 + nh + j * 16 + lr;
        if (n < N) {
            float bv = bias[n];
#pragma unroll
            for (int i = 0; i < 4; i++) {
                int mb = m0 + mh + i * 16 + lk * 4;
                if (OUT_MODE == 2) {
                    u16x4 o;
#pragma unroll
                    for (int r = 0; r < 4; r++) o[r] = f2bf(acc[i][j][r] + bv);
                    *(u16x4*)((u16*)C + (size_t)n * BSZ + mb) = o;
                } else {
#pragma unroll
                    for (int r = 0; r < 4; r++) {
                        float v = acc[i][j][r] + bv;
                        if (OUT_MODE == 1) ((u16*)C)[(size_t)(mb + r) * N + n] = f2bf(v);
                        else               ((float*)C)[(size_t)(mb + r) * N + n] = v;
                    }
                }
            }
        }
    }
}

// ---------- bilinear, v5: BM=256, 64 rows/wave, register-dieted ----------
// z = sum_s h0[:,s] * (h1 @ Wb[c,:,s,:]^T).
// v5 vs v4 (which spilled at the 128 arch-VGPR cap; conflicts proven to be
// gl2lds-DMA-write bound and halved by BM=256):
//  * h0 comes in TRANSPOSED (h0T[MM][B], written by gemm1 mode2): per step
//    4x u16x4 row-contiguous loads (was 16 scalar column-gathers). h0
//    double-buffer 32 -> 16 VGPRs; addressing = 1 uniform ptr + 1 voffset.
//  * Ws staging: 1 uniform ptr (SGPR, +80/s) + 4x 32-bit per-lane offsets.
//  * steady arch est: av 48 + h0 bufs 16 + h0f 16 + wsoff 4 + misc ~12 +
//    transients (bv 12, P 16) ~ 120 < 128; z[4][5]=80 in the acc half.
// vmcnt ledger: each step issues 4 stage + 4 h0T = 8 -> vmcnt(8) retires
// the previous step's stage and this step's h0 operand exactly.
__global__ __launch_bounds__(256, 2) void bilinear_k(
    const u16* __restrict__ h0T,   // [MMD][BSZ]
    const u16* __restrict__ h1g,   // [BSZ][MMD]
    const u16* __restrict__ Wbg, const float* __restrict__ bbg,
    u16* __restrict__ zg) {
    constexpr int WROW = 96;              // u16 per Ws row (12 octets)
    constexpr int WBUF = CSZ * WROW;      // 7680 u16 per buffer
    __shared__ __align__(16) u16 Ws[3 * WBUF];   // 46080 B
    const int tid = threadIdx.x, w = tid >> 6, lane = tid & 63;
    const int lr = lane & 15, lk = lane >> 4;
    const int m0 = blockIdx.x * 256, c = blockIdx.y;

    // zero pad octets (o = 10, 11) of every row, all 3 buffers (480 stores)
#pragma unroll
    for (int t = 0; t < 2; ++t) {
        int q = t * 256 + tid;
        if (q < 480) {
            int b = q / 160, r2 = q - b * 160;
            *(fvec4*)(Ws + b * WBUF + (r2 >> 1) * WROW + 80 + (r2 & 1) * 8) =
                (fvec4){0.f, 0.f, 0.f, 0.f};
        }
    }

    // Ws staging: 960 octet-positions (80 rows x 12), real o<10 (800).
    // it<3: p = it*256+tid. it==3: 192 tail octets, 48/wave (lanes 0..47).
    // Every wave has active lanes in all 4 its -> exactly 4 gl2lds/wave.
    int wsoff[4];   // per-lane source offset within Wb[c], u16 units
    bool wok[4];
    int wdst[4];    // LDS dest offset, u16 units (wave-uniform)
#pragma unroll
    for (int it = 0; it < 4; ++it) {
        int p, dstoct;
        if (it < 3) { p = it * 256 + tid;                        dstoct = it * 256 + w * 64; }
        else        { p = 768 + w * 48 + (lane < 48 ? lane : 0); dstoct = 768 + w * 48; }
        int row = p / 12, o = p - row * 12;
        wok[it] = (o < 10) && (it < 3 || lane < 48);
        wsoff[it] = row * 6400 + o * 8;
        wdst[it] = dstoct * 8;
    }

    // hoist A fragments (s-invariant) straight from global; zero the k>=80 pad
    bf16x8 av[4][3];
    {
        const u16* h1base = h1g + (size_t)m0 * MMD + c * CSZ;
#pragma unroll
        for (int i = 0; i < 4; ++i) {
            const u16* rowp = h1base + (size_t)(w * 64 + i * 16 + lr) * MMD;
#pragma unroll
            for (int st = 0; st < 3; ++st) {
                if (st == 2 && lk >= 2) {
                    av[i][st] = (bf16x8){0, 0, 0, 0, 0, 0, 0, 0};
                } else {
                    av[i][st] = *(const bf16x8*)(rowp + st * 32 + lk * 8);
                }
            }
        }
    }

    // h0T addressing: uniform row pointer (advances +BSZ per s) + one voffset
    const int vh = w * 64 + lk * 4;  // per-lane col base within the 256-row tile

    // prologue: stage buf0 (s=0); h0T row 0 -> HA
    const u16* WgS = Wbg + (size_t)c * CSZ * 6400;
#pragma unroll
    for (int it = 0; it < 4; ++it)
        if (wok[it]) gl2lds16(WgS + wsoff[it], Ws + wdst[it]);
    WgS += CSZ;
    const u16* hTn = h0T + (size_t)c * CSZ * BSZ + m0;
    u16x4 HA[4], HB[4];
#pragma unroll
    for (int i = 0; i < 4; ++i) HA[i] = *(const u16x4*)(hTn + vh + i * 16);
    hTn += BSZ;

    __syncthreads();   // full drain: pads + buf0 + av + HA all resolved

    const int boff0 = lr * WROW + lk * 8;
    f32x4 z[4][5] = {};
    const f32x4 zf = {0.f, 0.f, 0.f, 0.f};
    int bufR = 0;

#define STEP(S, HU, HL, LASTQ)                                              \
    {                                                                       \
        if (!(LASTQ)) {                                                     \
            u16* wW = Ws + ((bufR + 1 == 3) ? 0 : bufR + 1) * WBUF;         \
            _Pragma("unroll")                                               \
            for (int it = 0; it < 4; ++it)                                  \
                if (wok[it]) gl2lds16(WgS + wsoff[it], wW + wdst[it]);      \
            WgS += CSZ;                                                     \
            _Pragma("unroll")                                               \
            for (int i = 0; i < 4; ++i)                                     \
                HL[i] = *(const u16x4*)(hTn + vh + i * 16);                 \
            hTn += BSZ;                                                     \
            asm volatile("s_waitcnt vmcnt(8)" ::: "memory");                \
        } else {                                                            \
            asm volatile("s_waitcnt vmcnt(0)" ::: "memory");                \
        }                                                                   \
        __builtin_amdgcn_s_barrier();                                       \
        asm volatile("" ::: "memory");                                      \
        const u16* Wr = Ws + bufR * WBUF;                                   \
        float h0f[16];                                                      \
        _Pragma("unroll")                                                   \
        for (int i = 0; i < 4; ++i)                                         \
            _Pragma("unroll")                                               \
            for (int r = 0; r < 4; ++r) {                                   \
                u32 bits = ((u32)(u16)HU[i][r]) << 16;                      \
                __builtin_memcpy(&h0f[i * 4 + r], &bits, 4);                \
            }                                                               \
        _Pragma("unroll")                                                   \
        for (int j = 0; j < 5; ++j) {                                       \
            bf16x8 bv0 = *(const bf16x8*)(Wr + boff0 + j * 1536);           \
            bf16x8 bv1 = *(const bf16x8*)(Wr + boff0 + j * 1536 + 32);      \
            bf16x8 bv2 = *(const bf16x8*)(Wr + boff0 + j * 1536 + 64);      \
            f32x4 P[4];                                                     \
            _Pragma("unroll")                                               \
            for (int i = 0; i < 4; ++i)                                     \
                P[i] = __builtin_amdgcn_mfma_f32_16x16x32_bf16(av[i][0], bv0, zf, 0, 0, 0); \
            _Pragma("unroll")                                               \
            for (int i = 0; i < 4; ++i)                                     \
                P[i] = __builtin_amdgcn_mfma_f32_16x16x32_bf16(av[i][1], bv1, P[i], 0, 0, 0); \
            _Pragma("unroll")                                               \
            for (int i = 0; i < 4; ++i)                                     \
                P[i] = __builtin_amdgcn_mfma_f32_16x16x32_bf16(av[i][2], bv2, P[i], 0, 0, 0); \
            _Pragma("unroll")                                               \
            for (int i = 0; i < 4; ++i)                                     \
                _Pragma("unroll")                                           \
                for (int r = 0; r < 4; ++r)                                 \
                    z[i][j][r] += h0f[i * 4 + r] * P[i][r];                 \
        }                                                                   \
        bufR = (bufR == 2) ? 0 : bufR + 1;                                  \
    }

#pragma unroll 1
    for (int s2 = 0; s2 < 80; s2 += 2) {
        STEP(s2,     HA, HB, false)
        STEP(s2 + 1, HB, HA, (s2 == 78))
    }
#undef STEP

    // epilogue: +bb, signed sqrt, per-row L2 norm over the 80 chunk cols
    float bbv[5];
#pragma unroll
    for (int j = 0; j < 5; j++) bbv[j] = bbg[c * CSZ + j * 16 + lr];
    float sq[4][4] = {};
#pragma unroll
    for (int i = 0; i < 4; i++)
#pragma unroll
        for (int j = 0; j < 5; j++)
#pragma unroll
            for (int r = 0; r < 4; r++) {
                float v = z[i][j][r] + bbv[j];
                float a = sqrtf(fabsf(v));
                v = (v < 0.f) ? -a : a;
                z[i][j][r] = v;
                sq[i][r] += v * v;
            }
#pragma unroll
    for (int d = 1; d < 16; d <<= 1)
#pragma unroll
        for (int i = 0; i < 4; i++)
#pragma unroll
            for (int r = 0; r < 4; r++)
                sq[i][r] += __shfl_xor(sq[i][r], d, 64);
    float sc[4][4];
#pragma unroll
    for (int i = 0; i < 4; i++)
#pragma unroll
        for (int r = 0; r < 4; r++)
            sc[i][r] = 1.f / fmaxf(sqrtf(sq[i][r]), 1e-12f);
#pragma unroll
    for (int i = 0; i < 4; i++)
#pragma unroll
        for (int r = 0; r < 4; r++) {
            int row = m0 + w * 64 + i * 16 + lk * 4 + r;
#pragma unroll
            for (int j = 0; j < 5; j++) {
                int col = c * CSZ + j * 16 + lr;
                zg[(size_t)row * MMD + col] = f2bf(z[i][j][r] * sc[i][r]);
            }
        }
}

// ---------- launcher ----------
extern "C" void kernel_launch(void* const* d_in, const int* in_sizes, int n_in,
                              void* d_out, int out_size, void* d_ws, size_t ws_size,
                              hipStream_t stream) {
    (void)in_sizes; (void)n_in; (void)out_size; (void)ws_size;
    const float* x0 = (const float*)d_in[0];
    const float* x1 = (const float*)d_in[1];
    const float* W0 = (const float*)d_in[2];
    const float* b0 = (const float*)d_in[3];
    const float* W1 = (const float*)d_in[4];
    const float* b1 = (const float*)d_in[5];
    const float* Wb = (const float*)d_in[6];
    const float* bb = (const float*)d_in[7];
    const float* Wo = (const float*)d_in[8];
    const float* bo = (const float*)d_in[9];

    char* ws = (char*)d_ws;
    size_t off = 0;
    auto alloc = [&](size_t bytes) { void* p = ws + off; off += (bytes + 255) & ~(size_t)255; return p; };
    u16* x0b = (u16*)alloc((size_t)BSZ * DIN * 2);
    u16* x1b = (u16*)alloc((size_t)BSZ * DIN * 2);
    u16* W0T = (u16*)alloc((size_t)1664 * DIN * 2);
    u16* W1T = (u16*)alloc((size_t)1664 * DIN * 2);
    u16* WbB = (u16*)alloc((size_t)NCH * CSZ * 6400 * 2);
    u16* WoT = (u16*)alloc((size_t)3072 * MMD * 2);
    u16* h0T = (u16*)alloc((size_t)MMD * BSZ * 2);   // transposed h0
    u16* h1  = (u16*)alloc((size_t)BSZ * MMD * 2);
    u16* z   = x0b;  // alias: x0b dead after first GEMM

    cast_bf16_k<<<dim3(16384), dim3(256), 0, stream>>>(x0, x0b, (BSZ * DIN) / 4);
    cast_bf16_k<<<dim3(16384), dim3(256), 0, stream>>>(x1, x1b, (BSZ * DIN) / 4);
    cast_bf16_k<<<dim3(10000), dim3(256), 0, stream>>>(Wb, WbB, (NCH * CSZ * 6400) / 4);
    transpose_cast_k<<<dim3(DIN / 32, 1664 / 32), dim3(256), 0, stream>>>(W0, W0T, DIN, MMD);
    transpose_cast_k<<<dim3(DIN / 32, 1664 / 32), dim3(256), 0, stream>>>(W1, W1T, DIN, MMD);
    transpose_cast_k<<<dim3(MMD / 32, 3072 / 32), dim3(256), 0, stream>>>(Wo, WoT, MMD, DOUT);
    gemm_bt_k<2><<<dim3(BSZ / 128, 13), dim3(256), 0, stream>>>(x0b, W0T, b0, h0T, DIN, MMD);
    gemm_bt_k<1><<<dim3(BSZ / 128, 13), dim3(256), 0, stream>>>(x1b, W1T, b1, h1, DIN, MMD);
    bilinear_k<<<dim3(BSZ / 256, NCH), dim3(256), 0, stream>>>(h0T, h1, WbB, bb, z);
    gemm_bt_k<0><<<dim3(BSZ / 128, 24), dim3(256), 0, stream>>>(z, WoT, bo, d_out, MMD, DOUT);
}